// Round 8
// baseline (628.282 us; speedup 1.0000x reference)
//
#include <hip/hip_runtime.h>

#define N_NODES 100000
#define P_PAIRS 3200000
#define IN_F    19
#define OUT_F   64
#define BN_EPS  1e-5f
#define SLOPE   0.01f
#define BSHIFT  8       // 256 keys per bucket
#define BUCKETS 391     // ceil(N_NODES / 256)
#define CAP     13312   // padded staging capacity per bucket (mean ~12.2k), 64B-aligned
#define CHUNK_P 6400    // pairs per bucket1 block (P / 6400 = 500 blocks)
#define NCH     4       // channel chunks
#define CH_F    16      // channels per chunk (32 B rows, 3.2 MB table -> L2-resident)

typedef __attribute__((ext_vector_type(8))) unsigned short u16x8;
typedef __attribute__((ext_vector_type(8))) short bf16x8;
typedef __attribute__((ext_vector_type(4))) float f32x4;

__device__ __forceinline__ float bf2f(unsigned short h) {
    return __uint_as_float(((unsigned)h) << 16);
}
__device__ __forceinline__ unsigned short f2bf(float f) {
    unsigned u = __float_as_uint(f);
    return (unsigned short)((u + 0x7FFF + ((u >> 16) & 1)) >> 16);  // RNE
}

// ---------------------------------------------------------------------------
// K1: xw = x @ W_conv  -> bf16 chunk-major table [4][N][16] (in d_out lower half)
// ---------------------------------------------------------------------------
__global__ __launch_bounds__(256) void k_input_gemm(
    const float* __restrict__ x, const float* __restrict__ Wc,
    unsigned short* __restrict__ xwb)
{
    __shared__ float sWc[IN_F * OUT_F];
    for (int i = threadIdx.x; i < IN_F * OUT_F; i += 256) sWc[i] = Wc[i];
    __syncthreads();
    int wave = threadIdx.x >> 6;
    int lane = threadIdx.x & 63;
    int n = blockIdx.x * 4 + wave;           // N divisible by 4
    const float* xr = x + n * IN_F;
    float acc = 0.f;
    #pragma unroll
    for (int k = 0; k < IN_F; ++k) acc += xr[k] * sWc[k * OUT_F + lane];
    xwb[(size_t)(lane >> 4) * (N_NODES * CH_F) + (size_t)n * CH_F + (lane & 15)] = f2bf(acc);
}

// ---------------------------------------------------------------------------
// K2: bucket phase 1 — bin pairs into per-bucket staging, reservations padded
// to 64 B lines (16 entries) so each stage line is written by exactly ONE
// block (kills cross-XCD partial-line writeback amplification).
// entry: bit31 valid | [24:17] key&255 | [16:0] value. Pad slots zeroed.
// ---------------------------------------------------------------------------
__global__ __launch_bounds__(256) void k_bucket1(
    const int* __restrict__ key, const int* __restrict__ val,
    int* __restrict__ cur, int* __restrict__ curReal,
    unsigned int* __restrict__ stage)
{
    __shared__ int hist[BUCKETS];
    __shared__ int base_s[BUCKETS];
    int t = threadIdx.x;
    for (int b = t; b < BUCKETS; b += 256) hist[b] = 0;
    __syncthreads();
    int p0 = blockIdx.x * CHUNK_P;
    for (int i = t; i < CHUNK_P; i += 256)
        atomicAdd(&hist[key[p0 + i] >> BSHIFT], 1);
    __syncthreads();
    for (int b = t; b < BUCKETS; b += 256) {
        int c = hist[b];
        if (c > 0) {
            int cp = (c + 15) & ~15;             // pad to 64 B line
            base_s[b] = atomicAdd(&cur[b], cp);
            atomicAdd(&curReal[b], c);
        } else base_s[b] = 0;
        hist[b] = 0;                             // reuse as local cursor
    }
    __syncthreads();
    for (int i = t; i < CHUNK_P; i += 256) {
        int k = key[p0 + i];
        int v = val[p0 + i];
        int bk = k >> BSHIFT;
        int pos = base_s[bk] + atomicAdd(&hist[bk], 1);
        if (pos < CAP)                           // overflow guard
            stage[(size_t)bk * CAP + pos] =
                0x80000000u | ((unsigned)(k & 255) << 17) | (unsigned)v;
    }
    __syncthreads();
    // zero this block's pad tails (lines already dirty in our L2 -> cheap)
    for (int b = t; b < BUCKETS; b += 256) {
        int c = hist[b];                         // placed count
        if (c > 0) {
            int cp = (c + 15) & ~15;
            for (int j = c; j < cp; ++j) {
                int pos = base_s[b] + j;
                if (pos < CAP) stage[(size_t)b * CAP + pos] = 0u;
            }
        }
    }
}

// ---------------------------------------------------------------------------
// K3: mini-scan of 391 REAL bucket totals -> adj base offsets
// ---------------------------------------------------------------------------
__global__ __launch_bounds__(512) void k_minscan(
    const int* __restrict__ cur, int* __restrict__ base)
{
    __shared__ int s[512];
    int t = threadIdx.x;
    int v = (t < BUCKETS) ? cur[t] : 0;
    s[t] = v;
    __syncthreads();
    for (int off = 1; off < 512; off <<= 1) {
        int tmp = (t >= off) ? s[t - off] : 0;
        __syncthreads();
        s[t] += tmp;
        __syncthreads();
    }
    if (t < BUCKETS) base[t] = s[t] - v;   // exclusive
}

// ---------------------------------------------------------------------------
// K4: bucket phase 2 — count valid entries per key, in-block scan -> off/len,
// then place into compact adj. One block per bucket; stage region fixed b*CAP.
// ---------------------------------------------------------------------------
__global__ __launch_bounds__(256) void k_bucket2(
    const unsigned int* __restrict__ stage, const int* __restrict__ cur,
    const int* __restrict__ base, int* __restrict__ adj,
    int* __restrict__ offK, int* __restrict__ lenK)
{
    __shared__ int cnt[256];
    __shared__ int s[256];
    __shared__ int cur_l[256];
    int b = blockIdx.x;
    int t = threadIdx.x;
    int m = cur[b]; if (m > CAP) m = CAP;
    size_t sbase = (size_t)b * CAP;
    cnt[t] = 0;
    __syncthreads();
    for (int i = t; i < m; i += 256) {
        unsigned v = stage[sbase + i];
        if (v & 0x80000000u) atomicAdd(&cnt[(v >> 17) & 0xFF], 1);
    }
    __syncthreads();
    int c = cnt[t];
    s[t] = c;
    __syncthreads();
    for (int off = 1; off < 256; off <<= 1) {
        int tmp = (t >= off) ? s[t - off] : 0;
        __syncthreads();
        s[t] += tmp;
        __syncthreads();
    }
    int keyoff = base[b] + s[t] - c;       // global exclusive offset for key
    int k = (b << BSHIFT) + t;
    if (k < N_NODES) { offK[k] = keyoff; lenK[k] = c; }
    cur_l[t] = keyoff;
    __syncthreads();
    for (int i = t; i < m; i += 256) {
        unsigned v = stage[sbase + i];
        if (v & 0x80000000u) {
            int kl = (v >> 17) & 0xFF;
            int pos = atomicAdd(&cur_l[kl], 1);
            adj[pos] = (int)(v & 0x1FFFF);
        }
    }
}

// ---------------------------------------------------------------------------
// K5: hop, one channel chunk: out_c[k] = scale * sum in_c[adj[seg(k)]] (+bias)
// 4 segments per wave: lane = (seg-slot 2b, row-slot 3b, chan-half 1b)
// ---------------------------------------------------------------------------
__global__ __launch_bounds__(256) void k_hop(
    const int* __restrict__ adj, const int* __restrict__ offK,
    const int* __restrict__ lenK, const unsigned short* __restrict__ tin,
    unsigned short* __restrict__ tout, const float* __restrict__ bcc)
{
    int lane = threadIdx.x & 63;
    int wv = threadIdx.x >> 6;
    int es  = lane >> 4;                   // segment slot 0..3
    int sub = (lane >> 1) & 7;             // row slot 0..7
    int cg  = lane & 1;                    // 8-chan half
    int k = (blockIdx.x * 4 + wv) * 4 + es;  // grid = N/16
    int len = lenK[k];
    int start = offK[k];
    int end = start + len;

    float acc[8];
    #pragma unroll
    for (int j = 0; j < 8; ++j) acc[j] = 0.f;

    for (int i = start + sub; i < end; i += 8) {
        int idx = __builtin_nontemporal_load(&adj[i]);
        u16x8 v = *(const u16x8*)(tin + (size_t)idx * CH_F + cg * 8);
        #pragma unroll
        for (int j = 0; j < 8; ++j) acc[j] += bf2f(v[j]);
    }
    #pragma unroll
    for (int m = 2; m < 16; m <<= 1) {     // reduce over sub (lane bits 1..3)
        #pragma unroll
        for (int j = 0; j < 8; ++j) acc[j] += __shfl_xor(acc[j], m, 64);
    }
    if ((lane & 14) == 0) {                // sub == 0
        float sc = (len > 0) ? 1.f / (float)len : 0.f;
        u16x8 o;
        if (bcc) {
            #pragma unroll
            for (int j = 0; j < 8; ++j) o[j] = f2bf(acc[j] * sc + bcc[cg * 8 + j]);
        } else {
            #pragma unroll
            for (int j = 0; j < 8; ++j) o[j] = f2bf(acc[j] * sc);
        }
        __builtin_nontemporal_store(o, (u16x8*)(tout + (size_t)k * CH_F + cg * 8));
    }
}

// ---------------------------------------------------------------------------
// K6: MLP via MFMA: h = cv @ Wm + bm  (+ BN partials, block-reduced in LDS)
// ---------------------------------------------------------------------------
__global__ __launch_bounds__(256) void k_mlp_mfma(
    const unsigned short* __restrict__ cvb, const float* __restrict__ Wm,
    const float* __restrict__ bm, float* __restrict__ h,
    float* __restrict__ bns)
{
    __shared__ float red[128];             // [sum 64][sumsq 64]
    if (threadIdx.x < 128) red[threadIdx.x] = 0.f;
    __syncthreads();

    int lane = threadIdx.x & 63;
    int q = lane >> 4;                     // quad: k-segment / D row group
    int c = lane & 15;                     // A row / D col (within tile)

    bf16x8 bf[4][2];
    #pragma unroll
    for (int t = 0; t < 4; ++t)
        #pragma unroll
        for (int kh = 0; kh < 2; ++kh)
            #pragma unroll
            for (int j = 0; j < 8; ++j)
                bf[t][kh][j] = (short)f2bf(Wm[(kh * 32 + q * 8 + j) * OUT_F + t * 16 + c]);
    float bmv[4];
    #pragma unroll
    for (int t = 0; t < 4; ++t) bmv[t] = bm[t * 16 + c];

    float s[4], s2[4];
    #pragma unroll
    for (int t = 0; t < 4; ++t) { s[t] = 0.f; s2[t] = 0.f; }

    int gw = (blockIdx.x * 256 + threadIdx.x) >> 6;
    int nw = gridDim.x * 4;
    const int NT = N_NODES / 16;           // 6250 row-tiles
    for (int tile = gw; tile < NT; tile += nw) {
        int r0 = tile * 16;
        size_t rowoff = (size_t)(r0 + c) * CH_F + (q & 1) * 8;
        bf16x8 a0 = *(const bf16x8*)(cvb + (size_t)(q >> 1) * (N_NODES * CH_F) + rowoff);
        bf16x8 a1 = *(const bf16x8*)(cvb + (size_t)(2 + (q >> 1)) * (N_NODES * CH_F) + rowoff);
        #pragma unroll
        for (int t = 0; t < 4; ++t) {
            f32x4 acc = {0.f, 0.f, 0.f, 0.f};
            acc = __builtin_amdgcn_mfma_f32_16x16x32_bf16(a0, bf[t][0], acc, 0, 0, 0);
            acc = __builtin_amdgcn_mfma_f32_16x16x32_bf16(a1, bf[t][1], acc, 0, 0, 0);
            #pragma unroll
            for (int r = 0; r < 4; ++r) {
                float hv = acc[r] + bmv[t];
                h[(size_t)(r0 + q * 4 + r) * OUT_F + t * 16 + c] = hv;
                s[t]  += hv;
                s2[t] += hv * hv;
            }
        }
    }
    #pragma unroll
    for (int t = 0; t < 4; ++t) {
        #pragma unroll
        for (int m = 16; m < 64; m <<= 1) {
            s[t]  += __shfl_xor(s[t],  m, 64);
            s2[t] += __shfl_xor(s2[t], m, 64);
        }
    }
    if (lane < 16) {
        #pragma unroll
        for (int t = 0; t < 4; ++t) {
            atomicAdd(&red[t * 16 + lane], s[t]);
            atomicAdd(&red[64 + t * 16 + lane], s2[t]);
        }
    }
    __syncthreads();
    if (threadIdx.x < 128) atomicAdd(&bns[threadIdx.x], red[threadIdx.x]);
}

// ---------------------------------------------------------------------------
// K7: BN normalize + LeakyReLU + residual (x @ W_res + b_res) + LeakyReLU
// ---------------------------------------------------------------------------
__global__ __launch_bounds__(256) void k_final(
    const float* __restrict__ x, const float* __restrict__ Wr,
    const float* __restrict__ br, const float* __restrict__ bns,
    const float* __restrict__ gamma, const float* __restrict__ beta,
    float* __restrict__ out)
{
    __shared__ float sWr[IN_F * OUT_F];
    for (int i = threadIdx.x; i < IN_F * OUT_F; i += 256) sWr[i] = Wr[i];
    __syncthreads();
    int wave = threadIdx.x >> 6;
    int lane = threadIdx.x & 63;
    int n = blockIdx.x * 4 + wave;
    const float inv_n = 1.f / (float)N_NODES;
    float mean = bns[lane] * inv_n;
    float var  = bns[64 + lane] * inv_n - mean * mean;
    float rstd = rsqrtf(var + BN_EPS);
    float g = gamma[lane], bt = beta[lane];

    const float* xr = x + n * IN_F;
    float r = br[lane];
    #pragma unroll
    for (int k = 0; k < IN_F; ++k) r += xr[k] * sWr[k * OUT_F + lane];

    float hv = out[(size_t)n * OUT_F + lane];
    float a = g * (hv - mean) * rstd + bt;
    a = (a >= 0.f) ? a : SLOPE * a;
    float y = a + r;
    out[(size_t)n * OUT_F + lane] = (y >= 0.f) ? y : SLOPE * y;
}

// ---------------------------------------------------------------------------
extern "C" void kernel_launch(void* const* d_in, const int* in_sizes, int n_in,
                              void* d_out, int out_size, void* d_ws, size_t ws_size,
                              hipStream_t stream) {
    const float* x     = (const float*)d_in[0];
    const int*   hidx  = (const int*)d_in[1];
    const int*   ni    = hidx;               // row 0: node idx
    const int*   ei    = hidx + P_PAIRS;     // row 1: edge idx
    const float* Wc    = (const float*)d_in[2];
    const float* bc    = (const float*)d_in[3];
    const float* Wm    = (const float*)d_in[4];
    const float* bm    = (const float*)d_in[5];
    const float* gamma = (const float*)d_in[6];
    const float* beta  = (const float*)d_in[7];
    const float* Wr    = (const float*)d_in[8];
    const float* br    = (const float*)d_in[9];
    float* out = (float*)d_out;

    // --- ws (~46.5 MB): [adjE P][adjN P][stage 391*13312 u32 / efb alias][bns]
    int* adjE = (int*)d_ws;
    int* adjN = adjE + P_PAIRS;
    unsigned int* stage = (unsigned int*)(adjN + P_PAIRS);
    unsigned short* efb = (unsigned short*)stage;        // [4][N][16], stage dead by then
    float* bns = (float*)(stage + (size_t)BUCKETS * CAP);
    unsigned short* cvb = (unsigned short*)adjE;         // [4][N][16], adjE dead after hop1

    // --- d_out lower half: xwb [4][N][16] bf16 (dead before h); upper: small arrays
    unsigned short* xwb = (unsigned short*)d_out;
    int* smalls = (int*)(out + (size_t)N_NODES * OUT_F / 2);
    int* curE      = smalls;                  // keep the 4 cursor arrays contiguous
    int* curN      = curE + BUCKETS;
    int* curRealE  = curN + BUCKETS;
    int* curRealN  = curRealE + BUCKETS;
    int* baseE     = curRealN + BUCKETS;
    int* baseN     = baseE + BUCKETS;
    int* offE      = baseN + BUCKETS;
    int* lenE      = offE + N_NODES;
    int* offN      = lenE + N_NODES;
    int* lenN      = offN + N_NODES;

    hipMemsetAsync(bns, 0, 128 * sizeof(float), stream);
    hipMemsetAsync(curE, 0, 4 * BUCKETS * sizeof(int), stream);

    k_input_gemm<<<N_NODES / 4, 256, 0, stream>>>(x, Wc, xwb);

    // edge-side CSR
    k_bucket1<<<P_PAIRS / CHUNK_P, 256, 0, stream>>>(ei, ni, curE, curRealE, stage);
    k_minscan<<<1, 512, 0, stream>>>(curRealE, baseE);
    k_bucket2<<<BUCKETS, 256, 0, stream>>>(stage, curE, baseE, adjE, offE, lenE);
    // node-side CSR (stage reused)
    k_bucket1<<<P_PAIRS / CHUNK_P, 256, 0, stream>>>(ni, ei, curN, curRealN, stage);
    k_minscan<<<1, 512, 0, stream>>>(curRealN, baseN);
    k_bucket2<<<BUCKETS, 256, 0, stream>>>(stage, curN, baseN, adjN, offN, lenN);

    // hop1: per-chunk L2-resident gathers (stage dead -> efb)
    for (int c = 0; c < NCH; ++c)
        k_hop<<<N_NODES / 16, 256, 0, stream>>>(
            adjE, offE, lenE,
            xwb + (size_t)c * N_NODES * CH_F,
            efb + (size_t)c * N_NODES * CH_F,
            (const float*)nullptr);

    // hop2: per-chunk (adjE dead -> cvb)
    for (int c = 0; c < NCH; ++c)
        k_hop<<<N_NODES / 16, 256, 0, stream>>>(
            adjN, offN, lenN,
            efb + (size_t)c * N_NODES * CH_F,
            cvb + (size_t)c * N_NODES * CH_F,
            bc + c * CH_F);

    k_mlp_mfma<<<256, 256, 0, stream>>>(cvb, Wm, bm, out, bns);
    k_final<<<N_NODES / 4, 256, 0, stream>>>(x, Wr, br, bns, gamma, beta, out);
}

// Round 9
// 568.887 us; speedup vs baseline: 1.1044x; 1.1044x over previous
//
#include <hip/hip_runtime.h>

#define N_NODES 100000
#define P_PAIRS 3200000
#define IN_F    19
#define OUT_F   64
#define BN_EPS  1e-5f
#define SLOPE   0.01f
#define BSHIFT  8       // 256 keys per bucket
#define BUCKETS 391     // ceil(N_NODES / 256)
#define CAP     9000    // staging capacity per bucket (mean 8184, sd ~90)
#define CHUNK_P 6400    // pairs per bucket1 block (P / 6400 = 500 blocks)
#define NCH     4       // channel chunks
#define CH_F    16      // channels per chunk (32 B rows, 3.2 MB table -> L2-resident)

typedef __attribute__((ext_vector_type(8))) unsigned short u16x8;
typedef __attribute__((ext_vector_type(8))) short bf16x8;
typedef __attribute__((ext_vector_type(4))) float f32x4;

__device__ __forceinline__ float bf2f(unsigned short h) {
    return __uint_as_float(((unsigned)h) << 16);
}
__device__ __forceinline__ unsigned short f2bf(float f) {
    unsigned u = __float_as_uint(f);
    return (unsigned short)((u + 0x7FFF + ((u >> 16) & 1)) >> 16);  // RNE
}

// ---------------------------------------------------------------------------
// K1: xw = x @ W_conv  -> bf16 chunk-major table [4][N][16] (in d_out lower half)
// ---------------------------------------------------------------------------
__global__ __launch_bounds__(256) void k_input_gemm(
    const float* __restrict__ x, const float* __restrict__ Wc,
    unsigned short* __restrict__ xwb)
{
    __shared__ float sWc[IN_F * OUT_F];
    for (int i = threadIdx.x; i < IN_F * OUT_F; i += 256) sWc[i] = Wc[i];
    __syncthreads();
    int wave = threadIdx.x >> 6;
    int lane = threadIdx.x & 63;
    int n = blockIdx.x * 4 + wave;           // N divisible by 4
    const float* xr = x + n * IN_F;
    float acc = 0.f;
    #pragma unroll
    for (int k = 0; k < IN_F; ++k) acc += xr[k] * sWc[k * OUT_F + lane];
    xwb[(size_t)(lane >> 4) * (N_NODES * CH_F) + (size_t)n * CH_F + (lane & 15)] = f2bf(acc);
}

// ---------------------------------------------------------------------------
// K2: bucket phase 1 — block-level counting sort into LDS, then stream each
// bucket's contiguous run to its reserved global slot (full-line bursts; kills
// the temporal write-amplification of one-at-a-time 4 B scattered stores).
// stage entry: (key & 255) << 17 | value  (both ids < 2^17)
// ---------------------------------------------------------------------------
__global__ __launch_bounds__(256) void k_bucket1(
    const int* __restrict__ key, const int* __restrict__ val,
    int* __restrict__ cur, unsigned int* __restrict__ stage)
{
    __shared__ int hist[BUCKETS];          // per-bucket count (preserved)
    __shared__ int s[512];                 // scan / local cursor
    __shared__ int gbase[BUCKETS];         // reserved global start
    __shared__ unsigned int scratch[CHUNK_P];
    int t = threadIdx.x;
    for (int b = t; b < BUCKETS; b += 256) hist[b] = 0;
    __syncthreads();
    int p0 = blockIdx.x * CHUNK_P;
    for (int i = t; i < CHUNK_P; i += 256)
        atomicAdd(&hist[key[p0 + i] >> BSHIFT], 1);
    __syncthreads();
    // 512-wide inclusive scan with 256 threads (2 elems/thread)
    s[t] = (t < BUCKETS) ? hist[t] : 0;
    s[t + 256] = (t + 256 < BUCKETS) ? hist[t + 256] : 0;
    __syncthreads();
    for (int off = 1; off < 512; off <<= 1) {
        int a0 = (t >= off) ? s[t - off] : 0;
        int a1 = s[t + 256 - off];         // t+256 >= off always (off<=256)
        __syncthreads();
        s[t] += a0;
        s[t + 256] += a1;
        __syncthreads();
    }
    // reserve global space; convert s to exclusive local cursor
    for (int b = t; b < 512; b += 256) {
        if (b < BUCKETS) {
            int c = hist[b];
            gbase[b] = (c > 0) ? atomicAdd(&cur[b], c) : 0;
            s[b] -= c;                     // exclusive start = local cursor
        }
    }
    __syncthreads();
    // pass 2: place packed entries at sorted LDS positions (key/val L2-warm)
    for (int i = t; i < CHUNK_P; i += 256) {
        int k = key[p0 + i];
        int v = val[p0 + i];
        int bk = k >> BSHIFT;
        int pos = atomicAdd(&s[bk], 1);
        scratch[pos] = ((unsigned)(k & 255) << 17) | (unsigned)v;
    }
    __syncthreads();
    // flush: 16 groups x 16 lanes; each group streams whole bucket runs
    int grp = t >> 4;
    int l16 = t & 15;
    for (int b = grp; b < BUCKETS; b += 16) {
        int c = hist[b];
        if (c > 0) {
            int lstart = s[b] - c;         // s[b] is inclusive end again
            int gstart = gbase[b];
            size_t sb = (size_t)b * CAP;
            for (int j = l16; j < c; j += 16)
                stage[sb + gstart + j] = scratch[lstart + j];
        }
    }
}

// ---------------------------------------------------------------------------
// K3: mini-scan of 391 bucket totals -> adj base offsets
// ---------------------------------------------------------------------------
__global__ __launch_bounds__(512) void k_minscan(
    const int* __restrict__ cur, int* __restrict__ base)
{
    __shared__ int s[512];
    int t = threadIdx.x;
    int v = (t < BUCKETS) ? cur[t] : 0;
    s[t] = v;
    __syncthreads();
    for (int off = 1; off < 512; off <<= 1) {
        int tmp = (t >= off) ? s[t - off] : 0;
        __syncthreads();
        s[t] += tmp;
        __syncthreads();
    }
    if (t < BUCKETS) base[t] = s[t] - v;   // exclusive
}

// ---------------------------------------------------------------------------
// K4: bucket phase 2 — per-key count + in-block scan -> off/len, then place.
// ---------------------------------------------------------------------------
__global__ __launch_bounds__(256) void k_bucket2(
    const unsigned int* __restrict__ stage, const int* __restrict__ cur,
    const int* __restrict__ base, int* __restrict__ adj,
    int* __restrict__ offK, int* __restrict__ lenK)
{
    __shared__ int cnt[256];
    __shared__ int s[256];
    __shared__ int cur_l[256];
    int b = blockIdx.x;
    int t = threadIdx.x;
    int m = cur[b]; if (m > CAP) m = CAP;
    size_t sbase = (size_t)b * CAP;
    cnt[t] = 0;
    __syncthreads();
    for (int i = t; i < m; i += 256)
        atomicAdd(&cnt[stage[sbase + i] >> 17], 1);
    __syncthreads();
    int c = cnt[t];
    s[t] = c;
    __syncthreads();
    for (int off = 1; off < 256; off <<= 1) {
        int tmp = (t >= off) ? s[t - off] : 0;
        __syncthreads();
        s[t] += tmp;
        __syncthreads();
    }
    int keyoff = base[b] + s[t] - c;       // global exclusive offset for key
    int k = (b << BSHIFT) + t;
    if (k < N_NODES) { offK[k] = keyoff; lenK[k] = c; }
    cur_l[t] = keyoff;
    __syncthreads();
    for (int i = t; i < m; i += 256) {
        unsigned v = stage[sbase + i];
        int kl = v >> 17;
        int pos = atomicAdd(&cur_l[kl], 1);
        adj[pos] = (int)(v & 0x1FFFF);
    }
}

// ---------------------------------------------------------------------------
// K5: hop, one channel chunk: out_c[k] = scale * sum in_c[adj[seg(k)]] (+bias)
// 4 segments per wave: lane = (seg-slot 2b, row-slot 3b, chan-half 1b)
// ---------------------------------------------------------------------------
__global__ __launch_bounds__(256) void k_hop(
    const int* __restrict__ adj, const int* __restrict__ offK,
    const int* __restrict__ lenK, const unsigned short* __restrict__ tin,
    unsigned short* __restrict__ tout, const float* __restrict__ bcc)
{
    int lane = threadIdx.x & 63;
    int wv = threadIdx.x >> 6;
    int es  = lane >> 4;                   // segment slot 0..3
    int sub = (lane >> 1) & 7;             // row slot 0..7
    int cg  = lane & 1;                    // 8-chan half
    int k = (blockIdx.x * 4 + wv) * 4 + es;  // grid = N/16
    int len = lenK[k];
    int start = offK[k];
    int end = start + len;

    float acc[8];
    #pragma unroll
    for (int j = 0; j < 8; ++j) acc[j] = 0.f;

    for (int i = start + sub; i < end; i += 8) {
        int idx = __builtin_nontemporal_load(&adj[i]);
        u16x8 v = *(const u16x8*)(tin + (size_t)idx * CH_F + cg * 8);
        #pragma unroll
        for (int j = 0; j < 8; ++j) acc[j] += bf2f(v[j]);
    }
    #pragma unroll
    for (int m = 2; m < 16; m <<= 1) {     // reduce over sub (lane bits 1..3)
        #pragma unroll
        for (int j = 0; j < 8; ++j) acc[j] += __shfl_xor(acc[j], m, 64);
    }
    if ((lane & 14) == 0) {                // sub == 0
        float sc = (len > 0) ? 1.f / (float)len : 0.f;
        u16x8 o;
        if (bcc) {
            #pragma unroll
            for (int j = 0; j < 8; ++j) o[j] = f2bf(acc[j] * sc + bcc[cg * 8 + j]);
        } else {
            #pragma unroll
            for (int j = 0; j < 8; ++j) o[j] = f2bf(acc[j] * sc);
        }
        __builtin_nontemporal_store(o, (u16x8*)(tout + (size_t)k * CH_F + cg * 8));
    }
}

// ---------------------------------------------------------------------------
// K6: MLP via MFMA: h = cv @ Wm + bm  (+ BN partials, block-reduced in LDS)
// ---------------------------------------------------------------------------
__global__ __launch_bounds__(256) void k_mlp_mfma(
    const unsigned short* __restrict__ cvb, const float* __restrict__ Wm,
    const float* __restrict__ bm, float* __restrict__ h,
    float* __restrict__ bns)
{
    __shared__ float red[128];             // [sum 64][sumsq 64]
    if (threadIdx.x < 128) red[threadIdx.x] = 0.f;
    __syncthreads();

    int lane = threadIdx.x & 63;
    int q = lane >> 4;                     // quad: k-segment / D row group
    int c = lane & 15;                     // A row / D col (within tile)

    bf16x8 bf[4][2];
    #pragma unroll
    for (int t = 0; t < 4; ++t)
        #pragma unroll
        for (int kh = 0; kh < 2; ++kh)
            #pragma unroll
            for (int j = 0; j < 8; ++j)
                bf[t][kh][j] = (short)f2bf(Wm[(kh * 32 + q * 8 + j) * OUT_F + t * 16 + c]);
    float bmv[4];
    #pragma unroll
    for (int t = 0; t < 4; ++t) bmv[t] = bm[t * 16 + c];

    float s[4], s2[4];
    #pragma unroll
    for (int t = 0; t < 4; ++t) { s[t] = 0.f; s2[t] = 0.f; }

    int gw = (blockIdx.x * 256 + threadIdx.x) >> 6;
    int nw = gridDim.x * 4;
    const int NT = N_NODES / 16;           // 6250 row-tiles
    for (int tile = gw; tile < NT; tile += nw) {
        int r0 = tile * 16;
        size_t rowoff = (size_t)(r0 + c) * CH_F + (q & 1) * 8;
        bf16x8 a0 = *(const bf16x8*)(cvb + (size_t)(q >> 1) * (N_NODES * CH_F) + rowoff);
        bf16x8 a1 = *(const bf16x8*)(cvb + (size_t)(2 + (q >> 1)) * (N_NODES * CH_F) + rowoff);
        #pragma unroll
        for (int t = 0; t < 4; ++t) {
            f32x4 acc = {0.f, 0.f, 0.f, 0.f};
            acc = __builtin_amdgcn_mfma_f32_16x16x32_bf16(a0, bf[t][0], acc, 0, 0, 0);
            acc = __builtin_amdgcn_mfma_f32_16x16x32_bf16(a1, bf[t][1], acc, 0, 0, 0);
            #pragma unroll
            for (int r = 0; r < 4; ++r) {
                float hv = acc[r] + bmv[t];
                h[(size_t)(r0 + q * 4 + r) * OUT_F + t * 16 + c] = hv;
                s[t]  += hv;
                s2[t] += hv * hv;
            }
        }
    }
    #pragma unroll
    for (int t = 0; t < 4; ++t) {
        #pragma unroll
        for (int m = 16; m < 64; m <<= 1) {
            s[t]  += __shfl_xor(s[t],  m, 64);
            s2[t] += __shfl_xor(s2[t], m, 64);
        }
    }
    if (lane < 16) {
        #pragma unroll
        for (int t = 0; t < 4; ++t) {
            atomicAdd(&red[t * 16 + lane], s[t]);
            atomicAdd(&red[64 + t * 16 + lane], s2[t]);
        }
    }
    __syncthreads();
    if (threadIdx.x < 128) atomicAdd(&bns[threadIdx.x], red[threadIdx.x]);
}

// ---------------------------------------------------------------------------
// K7: BN normalize + LeakyReLU + residual (x @ W_res + b_res) + LeakyReLU
// ---------------------------------------------------------------------------
__global__ __launch_bounds__(256) void k_final(
    const float* __restrict__ x, const float* __restrict__ Wr,
    const float* __restrict__ br, const float* __restrict__ bns,
    const float* __restrict__ gamma, const float* __restrict__ beta,
    float* __restrict__ out)
{
    __shared__ float sWr[IN_F * OUT_F];
    for (int i = threadIdx.x; i < IN_F * OUT_F; i += 256) sWr[i] = Wr[i];
    __syncthreads();
    int wave = threadIdx.x >> 6;
    int lane = threadIdx.x & 63;
    int n = blockIdx.x * 4 + wave;
    const float inv_n = 1.f / (float)N_NODES;
    float mean = bns[lane] * inv_n;
    float var  = bns[64 + lane] * inv_n - mean * mean;
    float rstd = rsqrtf(var + BN_EPS);
    float g = gamma[lane], bt = beta[lane];

    const float* xr = x + n * IN_F;
    float r = br[lane];
    #pragma unroll
    for (int k = 0; k < IN_F; ++k) r += xr[k] * sWr[k * OUT_F + lane];

    float hv = out[(size_t)n * OUT_F + lane];
    float a = g * (hv - mean) * rstd + bt;
    a = (a >= 0.f) ? a : SLOPE * a;
    float y = a + r;
    out[(size_t)n * OUT_F + lane] = (y >= 0.f) ? y : SLOPE * y;
}

// ---------------------------------------------------------------------------
extern "C" void kernel_launch(void* const* d_in, const int* in_sizes, int n_in,
                              void* d_out, int out_size, void* d_ws, size_t ws_size,
                              hipStream_t stream) {
    const float* x     = (const float*)d_in[0];
    const int*   hidx  = (const int*)d_in[1];
    const int*   ni    = hidx;               // row 0: node idx
    const int*   ei    = hidx + P_PAIRS;     // row 1: edge idx
    const float* Wc    = (const float*)d_in[2];
    const float* bc    = (const float*)d_in[3];
    const float* Wm    = (const float*)d_in[4];
    const float* bm    = (const float*)d_in[5];
    const float* gamma = (const float*)d_in[6];
    const float* beta  = (const float*)d_in[7];
    const float* Wr    = (const float*)d_in[8];
    const float* br    = (const float*)d_in[9];
    float* out = (float*)d_out;

    // --- ws (~40 MB): [adjE P][adjN P][stage 391*9000 u32 / efb alias][bns]
    int* adjE = (int*)d_ws;
    int* adjN = adjE + P_PAIRS;
    unsigned int* stage = (unsigned int*)(adjN + P_PAIRS);
    unsigned short* efb = (unsigned short*)stage;        // [4][N][16], stage dead by then
    float* bns = (float*)(stage + (size_t)BUCKETS * CAP);
    unsigned short* cvb = (unsigned short*)adjE;         // [4][N][16], adjE dead after hop1

    // --- d_out lower half: xwb [4][N][16] bf16 (dead before h); upper: small arrays
    unsigned short* xwb = (unsigned short*)d_out;
    int* smalls = (int*)(out + (size_t)N_NODES * OUT_F / 2);
    int* curE  = smalls;
    int* curN  = curE + BUCKETS;
    int* baseE = curN + BUCKETS;
    int* baseN = baseE + BUCKETS;
    int* offE  = baseN + BUCKETS;
    int* lenE  = offE + N_NODES;
    int* offN  = lenE + N_NODES;
    int* lenN  = offN + N_NODES;

    hipMemsetAsync(bns, 0, 128 * sizeof(float), stream);
    hipMemsetAsync(curE, 0, 2 * BUCKETS * sizeof(int), stream);

    k_input_gemm<<<N_NODES / 4, 256, 0, stream>>>(x, Wc, xwb);

    // edge-side CSR
    k_bucket1<<<P_PAIRS / CHUNK_P, 256, 0, stream>>>(ei, ni, curE, stage);
    k_minscan<<<1, 512, 0, stream>>>(curE, baseE);
    k_bucket2<<<BUCKETS, 256, 0, stream>>>(stage, curE, baseE, adjE, offE, lenE);
    // node-side CSR (stage reused)
    k_bucket1<<<P_PAIRS / CHUNK_P, 256, 0, stream>>>(ni, ei, curN, stage);
    k_minscan<<<1, 512, 0, stream>>>(curN, baseN);
    k_bucket2<<<BUCKETS, 256, 0, stream>>>(stage, curN, baseN, adjN, offN, lenN);

    // hop1: per-chunk L2-resident gathers (stage dead -> efb)
    for (int c = 0; c < NCH; ++c)
        k_hop<<<N_NODES / 16, 256, 0, stream>>>(
            adjE, offE, lenE,
            xwb + (size_t)c * N_NODES * CH_F,
            efb + (size_t)c * N_NODES * CH_F,
            (const float*)nullptr);

    // hop2: per-chunk (adjE dead -> cvb)
    for (int c = 0; c < NCH; ++c)
        k_hop<<<N_NODES / 16, 256, 0, stream>>>(
            adjN, offN, lenN,
            efb + (size_t)c * N_NODES * CH_F,
            cvb + (size_t)c * N_NODES * CH_F,
            bc + c * CH_F);

    k_mlp_mfma<<<256, 256, 0, stream>>>(cvb, Wm, bm, out, bns);
    k_final<<<N_NODES / 4, 256, 0, stream>>>(x, Wr, br, bns, gamma, beta, out);
}

// Round 10
// 523.114 us; speedup vs baseline: 1.2010x; 1.0875x over previous
//
#include <hip/hip_runtime.h>

#define N_NODES 100000
#define P_PAIRS 3200000
#define IN_F    19
#define OUT_F   64
#define BN_EPS  1e-5f
#define SLOPE   0.01f
#define BSHIFT  8       // 256 keys per bucket
#define BUCKETS 391     // ceil(N_NODES / 256)
#define CAP     9000    // staging capacity per bucket (mean 8184, sd ~90)
#define CHUNK_P 6400    // pairs per bucket1 block (P / 6400 = 500 blocks)
#define NCH     4       // channel chunks
#define CH_F    16      // channels per chunk (32 B rows, 3.2 MB table -> L2-resident)

typedef __attribute__((ext_vector_type(8))) unsigned short u16x8;
typedef __attribute__((ext_vector_type(8))) short bf16x8;
typedef __attribute__((ext_vector_type(4))) float f32x4;

__device__ __forceinline__ float bf2f(unsigned short h) {
    return __uint_as_float(((unsigned)h) << 16);
}
__device__ __forceinline__ unsigned short f2bf(float f) {
    unsigned u = __float_as_uint(f);
    return (unsigned short)((u + 0x7FFF + ((u >> 16) & 1)) >> 16);  // RNE
}

// ---------------------------------------------------------------------------
// K1: xw = x @ W_conv -> bf16 chunk-major [4][N][16]. Weight column in VGPRs
// (19 regs/lane), grid-stride over node PAIRS (2-unroll: ILP + full-line
// chunk stores since (n, n+1) spans a 64 B line per chunk). No LDS staging.
// ---------------------------------------------------------------------------
__global__ __launch_bounds__(256) void k_input_gemm(
    const float* __restrict__ x, const float* __restrict__ Wc,
    unsigned short* __restrict__ xwb)
{
    int lane = threadIdx.x & 63;
    float w[IN_F];
    #pragma unroll
    for (int k = 0; k < IN_F; ++k) w[k] = Wc[k * OUT_F + lane];
    size_t coff = (size_t)(lane >> 4) * (N_NODES * CH_F) + (lane & 15);

    int gw = (blockIdx.x * 256 + threadIdx.x) >> 6;
    int nw = gridDim.x * 4;
    for (int n = gw * 2; n < N_NODES; n += nw * 2) {   // N even
        const float* xr0 = x + (size_t)n * IN_F;
        const float* xr1 = xr0 + IN_F;
        float a0 = 0.f, a1 = 0.f;
        #pragma unroll
        for (int k = 0; k < IN_F; ++k) {
            a0 += xr0[k] * w[k];
            a1 += xr1[k] * w[k];
        }
        xwb[coff + (size_t)n * CH_F]       = f2bf(a0);
        xwb[coff + (size_t)(n + 1) * CH_F] = f2bf(a1);
    }
}

// ---------------------------------------------------------------------------
// K2: bucket phase 1 — block-level counting sort into LDS, then stream each
// bucket's contiguous run to its reserved global slot. 512 threads.
// stage entry: (key & 255) << 17 | value  (both ids < 2^17)
// ---------------------------------------------------------------------------
__global__ __launch_bounds__(512) void k_bucket1(
    const int* __restrict__ key, const int* __restrict__ val,
    int* __restrict__ cur, unsigned int* __restrict__ stage)
{
    __shared__ int hist[BUCKETS];          // per-bucket count (preserved)
    __shared__ int s[512];                 // scan / local cursor
    __shared__ int gbase[BUCKETS];         // reserved global start
    __shared__ unsigned int scratch[CHUNK_P];
    int t = threadIdx.x;
    for (int b = t; b < BUCKETS; b += 512) hist[b] = 0;
    __syncthreads();
    int p0 = blockIdx.x * CHUNK_P;
    for (int i = t; i < CHUNK_P; i += 512)
        atomicAdd(&hist[key[p0 + i] >> BSHIFT], 1);
    __syncthreads();
    // 512-wide inclusive scan
    s[t] = (t < BUCKETS) ? hist[t] : 0;
    __syncthreads();
    for (int off = 1; off < 512; off <<= 1) {
        int tmp = (t >= off) ? s[t - off] : 0;
        __syncthreads();
        if (t >= off) s[t] += tmp;
        __syncthreads();
    }
    // reserve global space; convert s to exclusive local cursor
    if (t < BUCKETS) {
        int c = hist[t];
        gbase[t] = (c > 0) ? atomicAdd(&cur[t], c) : 0;
        s[t] -= c;
    }
    __syncthreads();
    // pass 2: place packed entries at sorted LDS positions (key/val L2-warm)
    for (int i = t; i < CHUNK_P; i += 512) {
        int k = key[p0 + i];
        int v = val[p0 + i];
        int bk = k >> BSHIFT;
        int pos = atomicAdd(&s[bk], 1);
        scratch[pos] = ((unsigned)(k & 255) << 17) | (unsigned)v;
    }
    __syncthreads();
    // flush: 32 groups x 16 lanes; each group streams whole bucket runs
    int grp = t >> 4;
    int l16 = t & 15;
    for (int b = grp; b < BUCKETS; b += 32) {
        int c = hist[b];
        if (c > 0) {
            int lstart = s[b] - c;         // s[b] is inclusive end again
            int gstart = gbase[b];
            size_t sb = (size_t)b * CAP;
            for (int j = l16; j < c; j += 16)
                stage[sb + gstart + j] = scratch[lstart + j];
        }
    }
}

// ---------------------------------------------------------------------------
// K3: mini-scan of 391 bucket totals -> adj base offsets
// ---------------------------------------------------------------------------
__global__ __launch_bounds__(512) void k_minscan(
    const int* __restrict__ cur, int* __restrict__ base)
{
    __shared__ int s[512];
    int t = threadIdx.x;
    int v = (t < BUCKETS) ? cur[t] : 0;
    s[t] = v;
    __syncthreads();
    for (int off = 1; off < 512; off <<= 1) {
        int tmp = (t >= off) ? s[t - off] : 0;
        __syncthreads();
        s[t] += tmp;
        __syncthreads();
    }
    if (t < BUCKETS) base[t] = s[t] - v;   // exclusive
}

// ---------------------------------------------------------------------------
// K4: bucket phase 2 — per-key count + in-block scan -> off/len, then place.
// 512 threads; 256-wide scan under guards (barriers unconditional).
// ---------------------------------------------------------------------------
__global__ __launch_bounds__(512) void k_bucket2(
    const unsigned int* __restrict__ stage, const int* __restrict__ cur,
    const int* __restrict__ base, int* __restrict__ adj,
    int* __restrict__ offK, int* __restrict__ lenK)
{
    __shared__ int cnt[256];
    __shared__ int s[256];
    __shared__ int cur_l[256];
    int b = blockIdx.x;
    int t = threadIdx.x;
    int m = cur[b]; if (m > CAP) m = CAP;
    size_t sbase = (size_t)b * CAP;
    if (t < 256) cnt[t] = 0;
    __syncthreads();
    for (int i = t; i < m; i += 512)
        atomicAdd(&cnt[stage[sbase + i] >> 17], 1);
    __syncthreads();
    int c = 0;
    if (t < 256) { c = cnt[t]; s[t] = c; }
    __syncthreads();
    for (int off = 1; off < 256; off <<= 1) {
        int tmp = 0;
        if (t < 256 && t >= off) tmp = s[t - off];
        __syncthreads();
        if (t < 256 && t >= off) s[t] += tmp;
        __syncthreads();
    }
    if (t < 256) {
        int keyoff = base[b] + s[t] - c;   // global exclusive offset for key
        int k = (b << BSHIFT) + t;
        if (k < N_NODES) { offK[k] = keyoff; lenK[k] = c; }
        cur_l[t] = keyoff;
    }
    __syncthreads();
    for (int i = t; i < m; i += 512) {
        unsigned v = stage[sbase + i];
        int kl = v >> 17;
        int pos = atomicAdd(&cur_l[kl], 1);
        adj[pos] = (int)(v & 0x1FFFF);
    }
}

// ---------------------------------------------------------------------------
// K5: hop, one channel chunk: out_c[k] = scale * sum in_c[adj[seg(k)]] (+bias)
// 4 segments per wave: lane = (seg-slot 2b, row-slot 3b, chan-half 1b)
// ---------------------------------------------------------------------------
__global__ __launch_bounds__(256) void k_hop(
    const int* __restrict__ adj, const int* __restrict__ offK,
    const int* __restrict__ lenK, const unsigned short* __restrict__ tin,
    unsigned short* __restrict__ tout, const float* __restrict__ bcc)
{
    int lane = threadIdx.x & 63;
    int wv = threadIdx.x >> 6;
    int es  = lane >> 4;                   // segment slot 0..3
    int sub = (lane >> 1) & 7;             // row slot 0..7
    int cg  = lane & 1;                    // 8-chan half
    int k = (blockIdx.x * 4 + wv) * 4 + es;  // grid = N/16
    int len = lenK[k];
    int start = offK[k];
    int end = start + len;

    float acc[8];
    #pragma unroll
    for (int j = 0; j < 8; ++j) acc[j] = 0.f;

    for (int i = start + sub; i < end; i += 8) {
        int idx = __builtin_nontemporal_load(&adj[i]);
        u16x8 v = *(const u16x8*)(tin + (size_t)idx * CH_F + cg * 8);
        #pragma unroll
        for (int j = 0; j < 8; ++j) acc[j] += bf2f(v[j]);
    }
    #pragma unroll
    for (int m = 2; m < 16; m <<= 1) {     // reduce over sub (lane bits 1..3)
        #pragma unroll
        for (int j = 0; j < 8; ++j) acc[j] += __shfl_xor(acc[j], m, 64);
    }
    if ((lane & 14) == 0) {                // sub == 0
        float sc = (len > 0) ? 1.f / (float)len : 0.f;
        u16x8 o;
        if (bcc) {
            #pragma unroll
            for (int j = 0; j < 8; ++j) o[j] = f2bf(acc[j] * sc + bcc[cg * 8 + j]);
        } else {
            #pragma unroll
            for (int j = 0; j < 8; ++j) o[j] = f2bf(acc[j] * sc);
        }
        __builtin_nontemporal_store(o, (u16x8*)(tout + (size_t)k * CH_F + cg * 8));
    }
}

// ---------------------------------------------------------------------------
// K6: MLP via MFMA: h = cv @ Wm + bm  (+ BN partials, block-reduced in LDS)
// ---------------------------------------------------------------------------
__global__ __launch_bounds__(256) void k_mlp_mfma(
    const unsigned short* __restrict__ cvb, const float* __restrict__ Wm,
    const float* __restrict__ bm, float* __restrict__ h,
    float* __restrict__ bns)
{
    __shared__ float red[128];             // [sum 64][sumsq 64]
    if (threadIdx.x < 128) red[threadIdx.x] = 0.f;
    __syncthreads();

    int lane = threadIdx.x & 63;
    int q = lane >> 4;                     // quad: k-segment / D row group
    int c = lane & 15;                     // A row / D col (within tile)

    bf16x8 bf[4][2];
    #pragma unroll
    for (int t = 0; t < 4; ++t)
        #pragma unroll
        for (int kh = 0; kh < 2; ++kh)
            #pragma unroll
            for (int j = 0; j < 8; ++j)
                bf[t][kh][j] = (short)f2bf(Wm[(kh * 32 + q * 8 + j) * OUT_F + t * 16 + c]);
    float bmv[4];
    #pragma unroll
    for (int t = 0; t < 4; ++t) bmv[t] = bm[t * 16 + c];

    float s[4], s2[4];
    #pragma unroll
    for (int t = 0; t < 4; ++t) { s[t] = 0.f; s2[t] = 0.f; }

    int gw = (blockIdx.x * 256 + threadIdx.x) >> 6;
    int nw = gridDim.x * 4;
    const int NT = N_NODES / 16;           // 6250 row-tiles
    for (int tile = gw; tile < NT; tile += nw) {
        int r0 = tile * 16;
        size_t rowoff = (size_t)(r0 + c) * CH_F + (q & 1) * 8;
        bf16x8 a0 = *(const bf16x8*)(cvb + (size_t)(q >> 1) * (N_NODES * CH_F) + rowoff);
        bf16x8 a1 = *(const bf16x8*)(cvb + (size_t)(2 + (q >> 1)) * (N_NODES * CH_F) + rowoff);
        #pragma unroll
        for (int t = 0; t < 4; ++t) {
            f32x4 acc = {0.f, 0.f, 0.f, 0.f};
            acc = __builtin_amdgcn_mfma_f32_16x16x32_bf16(a0, bf[t][0], acc, 0, 0, 0);
            acc = __builtin_amdgcn_mfma_f32_16x16x32_bf16(a1, bf[t][1], acc, 0, 0, 0);
            #pragma unroll
            for (int r = 0; r < 4; ++r) {
                float hv = acc[r] + bmv[t];
                h[(size_t)(r0 + q * 4 + r) * OUT_F + t * 16 + c] = hv;
                s[t]  += hv;
                s2[t] += hv * hv;
            }
        }
    }
    #pragma unroll
    for (int t = 0; t < 4; ++t) {
        #pragma unroll
        for (int m = 16; m < 64; m <<= 1) {
            s[t]  += __shfl_xor(s[t],  m, 64);
            s2[t] += __shfl_xor(s2[t], m, 64);
        }
    }
    if (lane < 16) {
        #pragma unroll
        for (int t = 0; t < 4; ++t) {
            atomicAdd(&red[t * 16 + lane], s[t]);
            atomicAdd(&red[64 + t * 16 + lane], s2[t]);
        }
    }
    __syncthreads();
    if (threadIdx.x < 128) atomicAdd(&bns[threadIdx.x], red[threadIdx.x]);
}

// ---------------------------------------------------------------------------
// K7: BN normalize + LeakyReLU + residual + LeakyReLU. Weight column in
// VGPRs, grid-stride over node pairs (no LDS staging).
// ---------------------------------------------------------------------------
__global__ __launch_bounds__(256) void k_final(
    const float* __restrict__ x, const float* __restrict__ Wr,
    const float* __restrict__ br, const float* __restrict__ bns,
    const float* __restrict__ gamma, const float* __restrict__ beta,
    float* __restrict__ out)
{
    int lane = threadIdx.x & 63;
    float w[IN_F];
    #pragma unroll
    for (int k = 0; k < IN_F; ++k) w[k] = Wr[k * OUT_F + lane];
    const float inv_n = 1.f / (float)N_NODES;
    float mean = bns[lane] * inv_n;
    float var  = bns[64 + lane] * inv_n - mean * mean;
    float rstd = rsqrtf(var + BN_EPS);
    float g = gamma[lane], bt = beta[lane];
    float rb = br[lane];

    int gw = (blockIdx.x * 256 + threadIdx.x) >> 6;
    int nw = gridDim.x * 4;
    for (int n = gw * 2; n < N_NODES; n += nw * 2) {
        const float* xr0 = x + (size_t)n * IN_F;
        const float* xr1 = xr0 + IN_F;
        float r0 = rb, r1 = rb;
        #pragma unroll
        for (int k = 0; k < IN_F; ++k) {
            r0 += xr0[k] * w[k];
            r1 += xr1[k] * w[k];
        }
        float hv0 = out[(size_t)n * OUT_F + lane];
        float hv1 = out[(size_t)(n + 1) * OUT_F + lane];
        float a0 = g * (hv0 - mean) * rstd + bt;
        float a1 = g * (hv1 - mean) * rstd + bt;
        a0 = (a0 >= 0.f) ? a0 : SLOPE * a0;
        a1 = (a1 >= 0.f) ? a1 : SLOPE * a1;
        float y0 = a0 + r0;
        float y1 = a1 + r1;
        out[(size_t)n * OUT_F + lane]       = (y0 >= 0.f) ? y0 : SLOPE * y0;
        out[(size_t)(n + 1) * OUT_F + lane] = (y1 >= 0.f) ? y1 : SLOPE * y1;
    }
}

// ---------------------------------------------------------------------------
extern "C" void kernel_launch(void* const* d_in, const int* in_sizes, int n_in,
                              void* d_out, int out_size, void* d_ws, size_t ws_size,
                              hipStream_t stream) {
    const float* x     = (const float*)d_in[0];
    const int*   hidx  = (const int*)d_in[1];
    const int*   ni    = hidx;               // row 0: node idx
    const int*   ei    = hidx + P_PAIRS;     // row 1: edge idx
    const float* Wc    = (const float*)d_in[2];
    const float* bc    = (const float*)d_in[3];
    const float* Wm    = (const float*)d_in[4];
    const float* bm    = (const float*)d_in[5];
    const float* gamma = (const float*)d_in[6];
    const float* beta  = (const float*)d_in[7];
    const float* Wr    = (const float*)d_in[8];
    const float* br    = (const float*)d_in[9];
    float* out = (float*)d_out;

    // --- ws (~40 MB): [adjE P][adjN P][stage 391*9000 u32 / efb alias][bns]
    int* adjE = (int*)d_ws;
    int* adjN = adjE + P_PAIRS;
    unsigned int* stage = (unsigned int*)(adjN + P_PAIRS);
    unsigned short* efb = (unsigned short*)stage;        // [4][N][16], stage dead by then
    float* bns = (float*)(stage + (size_t)BUCKETS * CAP);
    unsigned short* cvb = (unsigned short*)adjE;         // [4][N][16], adjE dead after hop1

    // --- d_out lower half: xwb [4][N][16] bf16 (dead before h); upper: small arrays
    unsigned short* xwb = (unsigned short*)d_out;
    int* smalls = (int*)(out + (size_t)N_NODES * OUT_F / 2);
    int* curE  = smalls;
    int* curN  = curE + BUCKETS;
    int* baseE = curN + BUCKETS;
    int* baseN = baseE + BUCKETS;
    int* offE  = baseN + BUCKETS;
    int* lenE  = offE + N_NODES;
    int* offN  = lenE + N_NODES;
    int* lenN  = offN + N_NODES;

    hipMemsetAsync(bns, 0, 128 * sizeof(float), stream);
    hipMemsetAsync(curE, 0, 2 * BUCKETS * sizeof(int), stream);

    k_input_gemm<<<256, 256, 0, stream>>>(x, Wc, xwb);

    // edge-side CSR
    k_bucket1<<<P_PAIRS / CHUNK_P, 512, 0, stream>>>(ei, ni, curE, stage);
    k_minscan<<<1, 512, 0, stream>>>(curE, baseE);
    k_bucket2<<<BUCKETS, 512, 0, stream>>>(stage, curE, baseE, adjE, offE, lenE);
    // node-side CSR (stage reused)
    k_bucket1<<<P_PAIRS / CHUNK_P, 512, 0, stream>>>(ni, ei, curN, stage);
    k_minscan<<<1, 512, 0, stream>>>(curN, baseN);
    k_bucket2<<<BUCKETS, 512, 0, stream>>>(stage, curN, baseN, adjN, offN, lenN);

    // hop1: per-chunk L2-resident gathers (stage dead -> efb)
    for (int c = 0; c < NCH; ++c)
        k_hop<<<N_NODES / 16, 256, 0, stream>>>(
            adjE, offE, lenE,
            xwb + (size_t)c * N_NODES * CH_F,
            efb + (size_t)c * N_NODES * CH_F,
            (const float*)nullptr);

    // hop2: per-chunk (adjE dead -> cvb)
    for (int c = 0; c < NCH; ++c)
        k_hop<<<N_NODES / 16, 256, 0, stream>>>(
            adjN, offN, lenN,
            efb + (size_t)c * N_NODES * CH_F,
            cvb + (size_t)c * N_NODES * CH_F,
            bc + c * CH_F);

    k_mlp_mfma<<<256, 256, 0, stream>>>(cvb, Wm, bm, out, bns);
    k_final<<<256, 256, 0, stream>>>(x, Wr, br, bns, gamma, beta, out);
}

// Round 11
// 465.190 us; speedup vs baseline: 1.3506x; 1.1245x over previous
//
#include <hip/hip_runtime.h>

#define N_NODES 100000
#define P_PAIRS 3200000
#define IN_F    19
#define OUT_F   64
#define BN_EPS  1e-5f
#define SLOPE   0.01f
#define BSHIFT  8       // 256 keys per bucket
#define BUCKETS 391     // ceil(N_NODES / 256)
#define CAP     9000    // staging capacity per bucket (mean 8184, sd ~90)
#define CHUNK_P 3200    // pairs per bucket1 block (P / 3200 = 1000 blocks)
#define NCH     4       // channel chunks
#define CH_F    16      // channels per chunk (32 B rows, 3.2 MB table -> L2-resident)

typedef __attribute__((ext_vector_type(8))) unsigned short u16x8;
typedef __attribute__((ext_vector_type(8))) short bf16x8;
typedef __attribute__((ext_vector_type(4))) float f32x4;

__device__ __forceinline__ float bf2f(unsigned short h) {
    return __uint_as_float(((unsigned)h) << 16);
}
__device__ __forceinline__ unsigned short f2bf(float f) {
    unsigned u = __float_as_uint(f);
    return (unsigned short)((u + 0x7FFF + ((u >> 16) & 1)) >> 16);  // RNE
}

// ---------------------------------------------------------------------------
// K1: xw = x @ W_conv -> bf16 chunk-major [4][N][16]. Weight column in VGPRs,
// grid-stride over node pairs (ILP + full-line chunk stores).
// ---------------------------------------------------------------------------
__global__ __launch_bounds__(256) void k_input_gemm(
    const float* __restrict__ x, const float* __restrict__ Wc,
    unsigned short* __restrict__ xwb)
{
    int lane = threadIdx.x & 63;
    float w[IN_F];
    #pragma unroll
    for (int k = 0; k < IN_F; ++k) w[k] = Wc[k * OUT_F + lane];
    size_t coff = (size_t)(lane >> 4) * (N_NODES * CH_F) + (lane & 15);

    int gw = (blockIdx.x * 256 + threadIdx.x) >> 6;
    int nw = gridDim.x * 4;
    for (int n = gw * 2; n < N_NODES; n += nw * 2) {   // N even
        const float* xr0 = x + (size_t)n * IN_F;
        const float* xr1 = xr0 + IN_F;
        float a0 = 0.f, a1 = 0.f;
        #pragma unroll
        for (int k = 0; k < IN_F; ++k) {
            a0 += xr0[k] * w[k];
            a1 += xr1[k] * w[k];
        }
        xwb[coff + (size_t)n * CH_F]       = f2bf(a0);
        xwb[coff + (size_t)(n + 1) * CH_F] = f2bf(a1);
    }
}

// ---------------------------------------------------------------------------
// K2: combined bucket phase 1 — BOTH sides in one pass over the pairs.
// Block-level counting sort into two LDS scratches, burst-flush each bucket
// run to its reserved global slot. 512 threads, 1000 blocks.
// stage entry: (key & 255) << 17 | value  (both ids < 2^17)
// ---------------------------------------------------------------------------
__global__ __launch_bounds__(512) void k_bucket1_both(
    const int* __restrict__ ni, const int* __restrict__ ei,
    int* __restrict__ curE, int* __restrict__ curN,
    unsigned int* __restrict__ stageE, unsigned int* __restrict__ stageN)
{
    __shared__ int histE[BUCKETS], histN[BUCKETS];
    __shared__ int cE[BUCKETS], cN[BUCKETS];
    __shared__ int gbE[BUCKETS], gbN[BUCKETS];
    __shared__ int s[512];
    __shared__ unsigned int scrE[CHUNK_P], scrN[CHUNK_P];
    int t = threadIdx.x;
    for (int b = t; b < BUCKETS; b += 512) { histE[b] = 0; histN[b] = 0; }
    __syncthreads();
    int p0 = blockIdx.x * CHUNK_P;
    for (int i = t; i < CHUNK_P; i += 512) {
        atomicAdd(&histE[ei[p0 + i] >> BSHIFT], 1);
        atomicAdd(&histN[ni[p0 + i] >> BSHIFT], 1);
    }
    __syncthreads();
    // scan edge-side
    s[t] = (t < BUCKETS) ? histE[t] : 0;
    __syncthreads();
    for (int off = 1; off < 512; off <<= 1) {
        int tmp = (t >= off) ? s[t - off] : 0;
        __syncthreads();
        if (t >= off) s[t] += tmp;
        __syncthreads();
    }
    if (t < BUCKETS) {
        int c = histE[t];
        gbE[t] = (c > 0) ? atomicAdd(&curE[t], c) : 0;
        cE[t] = s[t] - c;                  // exclusive local cursor
    }
    __syncthreads();
    // scan node-side
    s[t] = (t < BUCKETS) ? histN[t] : 0;
    __syncthreads();
    for (int off = 1; off < 512; off <<= 1) {
        int tmp = (t >= off) ? s[t - off] : 0;
        __syncthreads();
        if (t >= off) s[t] += tmp;
        __syncthreads();
    }
    if (t < BUCKETS) {
        int c = histN[t];
        gbN[t] = (c > 0) ? atomicAdd(&curN[t], c) : 0;
        cN[t] = s[t] - c;
    }
    __syncthreads();
    // pass 2: place packed entries at sorted LDS positions (L2-warm re-read)
    for (int i = t; i < CHUNK_P; i += 512) {
        int n = ni[p0 + i];
        int e = ei[p0 + i];
        int pE = atomicAdd(&cE[e >> BSHIFT], 1);
        scrE[pE] = ((unsigned)(e & 255) << 17) | (unsigned)n;
        int pN = atomicAdd(&cN[n >> BSHIFT], 1);
        scrN[pN] = ((unsigned)(n & 255) << 17) | (unsigned)e;
    }
    __syncthreads();
    // flush: 32 groups x 16 lanes stream whole bucket runs (full-line bursts)
    int grp = t >> 4, l16 = t & 15;
    for (int b = grp; b < BUCKETS; b += 32) {
        int c = histE[b];
        if (c > 0) {
            int ls = cE[b] - c;            // cE[b] is inclusive end now
            int gs = gbE[b];
            size_t sb = (size_t)b * CAP;
            for (int j = l16; j < c; j += 16)
                if (gs + j < CAP) stageE[sb + gs + j] = scrE[ls + j];
        }
        c = histN[b];
        if (c > 0) {
            int ls = cN[b] - c;
            int gs = gbN[b];
            size_t sb = (size_t)b * CAP;
            for (int j = l16; j < c; j += 16)
                if (gs + j < CAP) stageN[sb + gs + j] = scrN[ls + j];
        }
    }
}

// ---------------------------------------------------------------------------
// K3: mini-scan of 391 bucket totals -> adj base offsets
// ---------------------------------------------------------------------------
__global__ __launch_bounds__(512) void k_minscan(
    const int* __restrict__ cur, int* __restrict__ base)
{
    __shared__ int s[512];
    int t = threadIdx.x;
    int v = (t < BUCKETS) ? cur[t] : 0;
    s[t] = v;
    __syncthreads();
    for (int off = 1; off < 512; off <<= 1) {
        int tmp = (t >= off) ? s[t - off] : 0;
        __syncthreads();
        s[t] += tmp;
        __syncthreads();
    }
    if (t < BUCKETS) base[t] = s[t] - v;   // exclusive
}

// ---------------------------------------------------------------------------
// K4: bucket phase 2 — per-key count + in-block scan -> off/len, then place.
// ---------------------------------------------------------------------------
__global__ __launch_bounds__(512) void k_bucket2(
    const unsigned int* __restrict__ stage, const int* __restrict__ cur,
    const int* __restrict__ base, int* __restrict__ adj,
    int* __restrict__ offK, int* __restrict__ lenK)
{
    __shared__ int cnt[256];
    __shared__ int s[256];
    __shared__ int cur_l[256];
    int b = blockIdx.x;
    int t = threadIdx.x;
    int m = cur[b]; if (m > CAP) m = CAP;
    size_t sbase = (size_t)b * CAP;
    if (t < 256) cnt[t] = 0;
    __syncthreads();
    for (int i = t; i < m; i += 512)
        atomicAdd(&cnt[stage[sbase + i] >> 17], 1);
    __syncthreads();
    int c = 0;
    if (t < 256) { c = cnt[t]; s[t] = c; }
    __syncthreads();
    for (int off = 1; off < 256; off <<= 1) {
        int tmp = 0;
        if (t < 256 && t >= off) tmp = s[t - off];
        __syncthreads();
        if (t < 256 && t >= off) s[t] += tmp;
        __syncthreads();
    }
    if (t < 256) {
        int keyoff = base[b] + s[t] - c;
        int k = (b << BSHIFT) + t;
        if (k < N_NODES) { offK[k] = keyoff; lenK[k] = c; }
        cur_l[t] = keyoff;
    }
    __syncthreads();
    for (int i = t; i < m; i += 512) {
        unsigned v = stage[sbase + i];
        int kl = v >> 17;
        int pos = atomicAdd(&cur_l[kl], 1);
        adj[pos] = (int)(v & 0x1FFFF);
    }
}

// ---------------------------------------------------------------------------
// K5: fused hop over all 4 channel chunks in one launch.
// chunk = blockIdx bits[2:1] -> (round-robin heuristic) chunk c lands on
// XCDs {2c,2c+1}, keeping each 3.2 MB table L2-resident per XCD.
// 4 segments per wave: lane = (seg 2b, row-slot 3b, chan-half 1b); 2-unroll.
// ---------------------------------------------------------------------------
__global__ __launch_bounds__(256) void k_hop(
    const int* __restrict__ adj, const int* __restrict__ offK,
    const int* __restrict__ lenK, const unsigned short* __restrict__ tin_base,
    unsigned short* __restrict__ tout_base, const float* __restrict__ bcc)
{
    int b = blockIdx.x;                    // grid = 25000
    int chunk = (b & 6) >> 1;
    int sb = ((b >> 3) << 1) | (b & 1);    // 0..6249
    const unsigned short* tin = tin_base + (size_t)chunk * (N_NODES * CH_F);
    unsigned short* tout = tout_base + (size_t)chunk * (N_NODES * CH_F);

    int lane = threadIdx.x & 63;
    int wv = threadIdx.x >> 6;
    int es  = lane >> 4;
    int sub = (lane >> 1) & 7;
    int cg  = lane & 1;
    int k = (sb * 4 + wv) * 4 + es;
    int len = lenK[k];
    int start = offK[k];
    int end = start + len;

    float acc[8];
    #pragma unroll
    for (int j = 0; j < 8; ++j) acc[j] = 0.f;

    int i = start + sub;
    for (; i + 8 < end; i += 16) {         // 2 gather chains in flight
        int i0 = __builtin_nontemporal_load(&adj[i]);
        int i1 = __builtin_nontemporal_load(&adj[i + 8]);
        u16x8 v0 = *(const u16x8*)(tin + (size_t)i0 * CH_F + cg * 8);
        u16x8 v1 = *(const u16x8*)(tin + (size_t)i1 * CH_F + cg * 8);
        #pragma unroll
        for (int j = 0; j < 8; ++j) acc[j] += bf2f(v0[j]);
        #pragma unroll
        for (int j = 0; j < 8; ++j) acc[j] += bf2f(v1[j]);
    }
    if (i < end) {
        int i0 = __builtin_nontemporal_load(&adj[i]);
        u16x8 v0 = *(const u16x8*)(tin + (size_t)i0 * CH_F + cg * 8);
        #pragma unroll
        for (int j = 0; j < 8; ++j) acc[j] += bf2f(v0[j]);
    }
    #pragma unroll
    for (int m = 2; m < 16; m <<= 1) {     // reduce over sub (lane bits 1..3)
        #pragma unroll
        for (int j = 0; j < 8; ++j) acc[j] += __shfl_xor(acc[j], m, 64);
    }
    if ((lane & 14) == 0) {                // sub == 0
        float sc = (len > 0) ? 1.f / (float)len : 0.f;
        u16x8 o;
        if (bcc) {
            #pragma unroll
            for (int j = 0; j < 8; ++j)
                o[j] = f2bf(acc[j] * sc + bcc[chunk * CH_F + cg * 8 + j]);
        } else {
            #pragma unroll
            for (int j = 0; j < 8; ++j) o[j] = f2bf(acc[j] * sc);
        }
        __builtin_nontemporal_store(o, (u16x8*)(tout + (size_t)k * CH_F + cg * 8));
    }
}

// ---------------------------------------------------------------------------
// K6: MLP via MFMA: h = cv @ Wm + bm  (+ BN partials, block-reduced in LDS)
// ---------------------------------------------------------------------------
__global__ __launch_bounds__(256) void k_mlp_mfma(
    const unsigned short* __restrict__ cvb, const float* __restrict__ Wm,
    const float* __restrict__ bm, float* __restrict__ h,
    float* __restrict__ bns)
{
    __shared__ float red[128];             // [sum 64][sumsq 64]
    if (threadIdx.x < 128) red[threadIdx.x] = 0.f;
    __syncthreads();

    int lane = threadIdx.x & 63;
    int q = lane >> 4;
    int c = lane & 15;

    bf16x8 bf[4][2];
    #pragma unroll
    for (int t = 0; t < 4; ++t)
        #pragma unroll
        for (int kh = 0; kh < 2; ++kh)
            #pragma unroll
            for (int j = 0; j < 8; ++j)
                bf[t][kh][j] = (short)f2bf(Wm[(kh * 32 + q * 8 + j) * OUT_F + t * 16 + c]);
    float bmv[4];
    #pragma unroll
    for (int t = 0; t < 4; ++t) bmv[t] = bm[t * 16 + c];

    float s[4], s2[4];
    #pragma unroll
    for (int t = 0; t < 4; ++t) { s[t] = 0.f; s2[t] = 0.f; }

    int gw = (blockIdx.x * 256 + threadIdx.x) >> 6;
    int nw = gridDim.x * 4;
    const int NT = N_NODES / 16;
    for (int tile = gw; tile < NT; tile += nw) {
        int r0 = tile * 16;
        size_t rowoff = (size_t)(r0 + c) * CH_F + (q & 1) * 8;
        bf16x8 a0 = *(const bf16x8*)(cvb + (size_t)(q >> 1) * (N_NODES * CH_F) + rowoff);
        bf16x8 a1 = *(const bf16x8*)(cvb + (size_t)(2 + (q >> 1)) * (N_NODES * CH_F) + rowoff);
        #pragma unroll
        for (int t = 0; t < 4; ++t) {
            f32x4 acc = {0.f, 0.f, 0.f, 0.f};
            acc = __builtin_amdgcn_mfma_f32_16x16x32_bf16(a0, bf[t][0], acc, 0, 0, 0);
            acc = __builtin_amdgcn_mfma_f32_16x16x32_bf16(a1, bf[t][1], acc, 0, 0, 0);
            #pragma unroll
            for (int r = 0; r < 4; ++r) {
                float hv = acc[r] + bmv[t];
                h[(size_t)(r0 + q * 4 + r) * OUT_F + t * 16 + c] = hv;
                s[t]  += hv;
                s2[t] += hv * hv;
            }
        }
    }
    #pragma unroll
    for (int t = 0; t < 4; ++t) {
        #pragma unroll
        for (int m = 16; m < 64; m <<= 1) {
            s[t]  += __shfl_xor(s[t],  m, 64);
            s2[t] += __shfl_xor(s2[t], m, 64);
        }
    }
    if (lane < 16) {
        #pragma unroll
        for (int t = 0; t < 4; ++t) {
            atomicAdd(&red[t * 16 + lane], s[t]);
            atomicAdd(&red[64 + t * 16 + lane], s2[t]);
        }
    }
    __syncthreads();
    if (threadIdx.x < 128) atomicAdd(&bns[threadIdx.x], red[threadIdx.x]);
}

// ---------------------------------------------------------------------------
// K7: BN normalize + LeakyReLU + residual + LeakyReLU (weights in VGPRs)
// ---------------------------------------------------------------------------
__global__ __launch_bounds__(256) void k_final(
    const float* __restrict__ x, const float* __restrict__ Wr,
    const float* __restrict__ br, const float* __restrict__ bns,
    const float* __restrict__ gamma, const float* __restrict__ beta,
    float* __restrict__ out)
{
    int lane = threadIdx.x & 63;
    float w[IN_F];
    #pragma unroll
    for (int k = 0; k < IN_F; ++k) w[k] = Wr[k * OUT_F + lane];
    const float inv_n = 1.f / (float)N_NODES;
    float mean = bns[lane] * inv_n;
    float var  = bns[64 + lane] * inv_n - mean * mean;
    float rstd = rsqrtf(var + BN_EPS);
    float g = gamma[lane], bt = beta[lane];
    float rb = br[lane];

    int gw = (blockIdx.x * 256 + threadIdx.x) >> 6;
    int nw = gridDim.x * 4;
    for (int n = gw * 2; n < N_NODES; n += nw * 2) {
        const float* xr0 = x + (size_t)n * IN_F;
        const float* xr1 = xr0 + IN_F;
        float r0 = rb, r1 = rb;
        #pragma unroll
        for (int k = 0; k < IN_F; ++k) {
            r0 += xr0[k] * w[k];
            r1 += xr1[k] * w[k];
        }
        float hv0 = out[(size_t)n * OUT_F + lane];
        float hv1 = out[(size_t)(n + 1) * OUT_F + lane];
        float a0 = g * (hv0 - mean) * rstd + bt;
        float a1 = g * (hv1 - mean) * rstd + bt;
        a0 = (a0 >= 0.f) ? a0 : SLOPE * a0;
        a1 = (a1 >= 0.f) ? a1 : SLOPE * a1;
        float y0 = a0 + r0;
        float y1 = a1 + r1;
        out[(size_t)n * OUT_F + lane]       = (y0 >= 0.f) ? y0 : SLOPE * y0;
        out[(size_t)(n + 1) * OUT_F + lane] = (y1 >= 0.f) ? y1 : SLOPE * y1;
    }
}

// ---------------------------------------------------------------------------
extern "C" void kernel_launch(void* const* d_in, const int* in_sizes, int n_in,
                              void* d_out, int out_size, void* d_ws, size_t ws_size,
                              hipStream_t stream) {
    const float* x     = (const float*)d_in[0];
    const int*   hidx  = (const int*)d_in[1];
    const int*   ni    = hidx;               // row 0: node idx
    const int*   ei    = hidx + P_PAIRS;     // row 1: edge idx
    const float* Wc    = (const float*)d_in[2];
    const float* bc    = (const float*)d_in[3];
    const float* Wm    = (const float*)d_in[4];
    const float* bm    = (const float*)d_in[5];
    const float* gamma = (const float*)d_in[6];
    const float* beta  = (const float*)d_in[7];
    const float* Wr    = (const float*)d_in[8];
    const float* br    = (const float*)d_in[9];
    float* out = (float*)d_out;

    // --- ws (~94 MB of the 256 MB workspace), no aliasing:
    int* adjE = (int*)d_ws;                                  // P
    int* adjN = adjE + P_PAIRS;                              // P
    unsigned int* stageE = (unsigned int*)(adjN + P_PAIRS);  // BUCKETS*CAP
    unsigned int* stageN = stageE + (size_t)BUCKETS * CAP;   // BUCKETS*CAP
    unsigned short* xwb = (unsigned short*)(stageN + (size_t)BUCKETS * CAP); // [4][N][16]
    unsigned short* efb = xwb + (size_t)NCH * N_NODES * CH_F;
    unsigned short* cvb = efb + (size_t)NCH * N_NODES * CH_F;
    float* bns = (float*)(cvb + (size_t)NCH * N_NODES * CH_F);
    int* curE  = (int*)(bns + 128);
    int* curN  = curE + BUCKETS;
    int* baseE = curN + BUCKETS;
    int* baseN = baseE + BUCKETS;
    int* offE  = baseN + BUCKETS;
    int* lenE  = offE + N_NODES;
    int* offN  = lenE + N_NODES;
    int* lenN  = offN + N_NODES;

    // zero bns + curE + curN (contiguous)
    hipMemsetAsync(bns, 0, (128 + 2 * BUCKETS) * sizeof(int), stream);

    k_input_gemm<<<256, 256, 0, stream>>>(x, Wc, xwb);

    k_bucket1_both<<<P_PAIRS / CHUNK_P, 512, 0, stream>>>(ni, ei, curE, curN, stageE, stageN);
    k_minscan<<<1, 512, 0, stream>>>(curE, baseE);
    k_minscan<<<1, 512, 0, stream>>>(curN, baseN);
    k_bucket2<<<BUCKETS, 512, 0, stream>>>(stageE, curE, baseE, adjE, offE, lenE);
    k_bucket2<<<BUCKETS, 512, 0, stream>>>(stageN, curN, baseN, adjN, offN, lenN);

    k_hop<<<25000, 256, 0, stream>>>(adjE, offE, lenE, xwb, efb, (const float*)nullptr);
    k_hop<<<25000, 256, 0, stream>>>(adjN, offN, lenN, efb, cvb, bc);

    k_mlp_mfma<<<256, 256, 0, stream>>>(cvb, Wm, bm, out, bns);
    k_final<<<256, 256, 0, stream>>>(x, Wr, br, bns, gamma, beta, out);
}